// Round 11
// baseline (52.100 us; speedup 1.0000x reference)
//
#include <hip/hip_runtime.h>

// Retrace loss: T=8192, K=2048, gamma=0.99.
// decay = cumprod(gamma*iw); S = reverse-cumsum(td*decay);
// retrace = S / max(decay,1e-10); loss = mean(smooth_l1(q, retrace)).
//
// f32 decay underflows to EXACT 0 within ~170 rows for every column
// (E[ln c]=-0.574, sd 0.83/step; at row 512 log-decay = -294 +- 18.7 =>
// alive prob ~1e-24). Once decay==0, retrace==0 in both our and the
// reference's arithmetic (absmax 0.0, rounds 6-10).
//
// Structure lessons (hard-won):
//  R7 : latency-bound chain co-scheduled with a BW flood stretches 5x.
//  R8 : __threadfence ticket in a wide grid = L2 writeback storm (448us).
//  R9 : f64 atomics on one address + ctrl on one cacheline = 50us ping-pong.
//  R10: zero-atomic partials + ballot flags -> 48us.
//  R11: kPre was the last slow piece (fused 4-stream read + LDS + chain
//       caps at ~1.5-2 TB/s demand, R1-R5). Split into its regimes:
//       kStage = PURE elementwise stream (m13 pattern) -> c,td staged;
//       kChain = register-only per-column chain (coalesced, MLP-native).

#define GAMMA 0.99f

constexpr int T_ = 8192;
constexpr int K_ = 2048;
constexpr int N_ = T_ - 1;               // 8191
constexpr int MROWS = 512;               // exact-prefix length
constexpr int L_ = 8;                    // rows per chunk
constexpr int MCH = MROWS / L_;          // 64 chunks
constexpr int NBPRE = MCH * (K_ / 256);  // 512 blocks (kChain and role A)
constexpr int NBTAIL = 2048;             // role-B blocks
constexpr int NBC = K_ / 256;            // 8 role-C blocks
constexpr int NBTOT = NBPRE + NBTAIL + NBC;  // 2568
constexpr int PREF4 = MROWS * K_ / 4;        // 262144 f4 elements
constexpr long long TAILF4 = (long long)(N_ - MROWS) * K_ / 4;  // 3,931,648

typedef float f4 __attribute__((ext_vector_type(4)));
typedef unsigned short us4 __attribute__((ext_vector_type(4)));

__device__ __forceinline__ unsigned short f2bf(float f) {  // RTNE
  unsigned u = __float_as_uint(f);
  u += 0x7FFFu + ((u >> 16) & 1u);
  return (unsigned short)(u >> 16);
}
__device__ __forceinline__ float bf2f(unsigned short h) {
  return __uint_as_float(((unsigned)h) << 16);
}
__device__ __forceinline__ float bfhi(unsigned q) {  // y in hi16
  return __uint_as_float(q & 0xFFFF0000u);
}
__device__ __forceinline__ float bflo(unsigned q) {  // ld in lo16
  return __uint_as_float(q << 16);
}
__device__ __forceinline__ float sl1(float dd) {
  float ad = fabsf(dd);
  return (ad < 1.f) ? 0.5f * dd * dd : ad - 0.5f;
}
// Block sum -> partials[bid] (plain store, no atomics).
__device__ __forceinline__ void block_reduce_store(float l, float* slot) {
  for (int off = 32; off > 0; off >>= 1) l += __shfl_down(l, off);
  __shared__ float wsum[4];
  const int lane = threadIdx.x & 63, wid = threadIdx.x >> 6;
  if (lane == 0) wsum[wid] = l;
  __syncthreads();
  if (threadIdx.x == 0) *slot = wsum[0] + wsum[1] + wsum[2] + wsum[3];
}

// ---------------------------------------------------------------- kStage
// Pure elementwise prefix stream: c = gamma*iw (f32), td (bf16).
// One f4 per thread, 1024 blocks, no chain, no LDS -> full MLP.
__global__ __launch_bounds__(256) void kStage(
    const float* __restrict__ tsv, const float* __restrict__ tev,
    const float* __restrict__ r, const float* __restrict__ ologp,
    const float* __restrict__ tlogp, float* __restrict__ cst,
    unsigned short* __restrict__ tdst) {
  const int e = blockIdx.x * 256 + threadIdx.x;  // 0..PREF4-1
  const int i = e >> 9;                          // row 0..511
  const int col = (e & 511) * 4;
  const size_t b1 = (size_t)(i + 1) * K_ + col;
  const size_t b0 = (size_t)i * K_ + col;
  f4 lw = *(const f4*)(tlogp + b1);
  f4 a = *(const f4*)(tsv + b1);
  f4 v = *(const f4*)(tev + b1);
  f4 rr = *(const f4*)(r + b0);
  const float o = ologp[i + 1];
  f4 iw, c, td;
#pragma unroll
  for (int x = 0; x < 4; ++x) iw[x] = __expf(fminf(lw[x] - o, 0.f));
#pragma unroll
  for (int x = 0; x < 4; ++x) c[x] = GAMMA * iw[x];
#pragma unroll
  for (int x = 0; x < 4; ++x)
    td[x] = fmaf(GAMMA, fmaf(-iw[x], a[x], v[x]), rr[x]);
  *(f4*)(cst + b0) = c;
  us4 t4;
#pragma unroll
  for (int x = 0; x < 4; ++x) t4[x] = f2bf(td[x]);
  *(us4*)(tdst + b0) = t4;
}

// ---------------------------------------------------------------- kChain
// Register-only chain: thread = (chunk, col). 8 independent coalesced
// loads of c/td (L2/L3-hot), chain in registers, packed bf16 store.
// Numerics identical to R10 kPre phase 2 (absmax 0.0 proven).
__global__ __launch_bounds__(256) void kChain(
    const float* __restrict__ cst, const unsigned short* __restrict__ tdst,
    unsigned* __restrict__ pkPre, float* __restrict__ P,
    float* __restrict__ Zl) {
  const int chunk = blockIdx.x >> 3;  // 0..63
  const int k = (blockIdx.x & 7) * 256 + threadIdx.x;
  const int i0 = chunk * L_;
  float c[L_], tdv[L_];
#pragma unroll
  for (int s = 0; s < L_; ++s) {  // independent loads first (MLP)
    c[s] = cst[(size_t)(i0 + s) * K_ + k];
    tdv[s] = bf2f(tdst[(size_t)(i0 + s) * K_ + k]);
  }
  float p = 1.f, zl = 0.f;
#pragma unroll
  for (int s = 0; s < L_; ++s) {
    p *= c[s];
    float y = tdv[s] * p;
    zl += y;
    pkPre[(size_t)(i0 + s) * K_ + k] = ((unsigned)f2bf(y) << 16) | f2bf(p);
  }
  P[(size_t)chunk * K_ + k] = p;
  Zl[(size_t)chunk * K_ + k] = zl;
}

// ---------------------------------------------------------------- kScan
// Per column: chunk prefix products D0, suffix sums Ssuf; per-wave ballot
// builds the alive bitmask (plain store, no atomics).
__global__ __launch_bounds__(256) void kScan(
    const float* __restrict__ P, const float* __restrict__ Zl,
    float* __restrict__ D0, float* __restrict__ Ssuf,
    unsigned long long* __restrict__ flag64) {
  const int k = blockIdx.x * 256 + threadIdx.x;  // 0..K-1
  float d = 1.f;
#pragma unroll 16
  for (int c = 0; c < MCH; ++c) {
    D0[(size_t)c * K_ + k] = d;
    d *= P[(size_t)c * K_ + k];
  }
  const unsigned long long m = __ballot(d != 0.f);  // alive mask, 64 cols
  if ((threadIdx.x & 63) == 0) flag64[k >> 6] = m;
  float ss = 0.f;
#pragma unroll 16
  for (int c = MCH - 1; c >= 0; --c) {
    Ssuf[(size_t)c * K_ + k] = ss;
    ss = fmaf(D0[(size_t)c * K_ + k], Zl[(size_t)c * K_ + k], ss);
  }
}

// ---------------------------------------------------------------- kApply
// Role A: prefix apply (dead cols). Role B: tail sl1(sv) (dead cols).
// Role C: exact serial fallback per alive column (never for this data).
// Every block writes its own partials slot. NO atomics, NO fences.
__global__ __launch_bounds__(256) void kApply(
    const float* __restrict__ sv, const float* __restrict__ tsv,
    const float* __restrict__ tev, const float* __restrict__ r,
    const float* __restrict__ ologp, const float* __restrict__ tlogp,
    const unsigned* __restrict__ pkPre, const float* __restrict__ D0,
    const float* __restrict__ Ssuf,
    const unsigned long long* __restrict__ flag64,
    unsigned* __restrict__ pkFull, float* __restrict__ partials) {
  const int bid = blockIdx.x;
  const int tid = threadIdx.x;

  if (bid < NBPRE) {  // ---- role A: prefix rows [0,512)
    const int myc = bid >> 3;
    const int k = (bid & 7) * 256 + tid;
    float loss = 0.f;
    if (!((flag64[k >> 6] >> (k & 63)) & 1ull)) {
      const float d0 = D0[(size_t)myc * K_ + k];
      const float ssuf = Ssuf[(size_t)myc * K_ + k];
      const int i0 = myc * L_;
      float slocal = 0.f;
#pragma unroll
      for (int s = L_ - 1; s >= 0; --s) {
        const size_t b0 = (size_t)(i0 + s) * K_ + k;
        unsigned q = pkPre[b0];
        slocal += bfhi(q);
        float S = fmaf(d0, slocal, ssuf);
        float retrace = S / fmaxf(d0 * bflo(q), 1e-10f);
        loss += sl1(sv[b0] - retrace);
      }
    }
    block_reduce_store(loss, partials + bid);
  } else if (bid < NBPRE + NBTAIL) {  // ---- role B: tail rows [512,8191)
    __shared__ unsigned long long fb[32];
    __shared__ unsigned anyAlive;
    if (tid < 32) fb[tid] = flag64[tid];
    __syncthreads();
    if (tid == 0) {
      unsigned long long o = 0ull;
#pragma unroll
      for (int j = 0; j < 32; ++j) o |= fb[j];
      anyAlive = (o != 0ull) ? 1u : 0u;
    }
    __syncthreads();
    const long long base = (long long)MROWS * K_ / 4;  // f4 offset
    float loss = 0.f;
    if (anyAlive == 0u) {  // fast path: all columns dead
      for (long long v = (long long)(bid - NBPRE) * 256 + tid; v < TAILF4;
           v += (long long)NBTAIL * 256) {
        f4 q = ((const f4*)sv)[base + v];
#pragma unroll
        for (int x = 0; x < 4; ++x) loss += sl1(q[x]);
      }
    } else {
      for (long long v = (long long)(bid - NBPRE) * 256 + tid; v < TAILF4;
           v += (long long)NBTAIL * 256) {
        f4 q = ((const f4*)sv)[base + v];
        const int k0 = (int)((v * 4) & (K_ - 1));
#pragma unroll
        for (int x = 0; x < 4; ++x) {
          const int k = k0 + x;
          if (!((fb[k >> 6] >> (k & 63)) & 1ull)) loss += sl1(q[x]);
        }
      }
    }
    block_reduce_store(loss, partials + bid);
  } else {  // ---- role C: exact fallback, thread per column (rare/never)
    const int k = (bid - NBPRE - NBTAIL) * 256 + tid;
    float loss = 0.f;
    if ((flag64[k >> 6] >> (k & 63)) & 1ull) {
      unsigned* mycol = pkFull + (size_t)k * 8192;
      float p = 1.f;
      for (int i = 0; i < N_; ++i) {  // forward: exact sequential decay
        const size_t b1 = (size_t)(i + 1) * K_ + k;
        float iw = __expf(fminf(tlogp[b1] - ologp[i + 1], 0.f));
        p *= GAMMA * iw;
        float td =
            fmaf(GAMMA, fmaf(-iw, tsv[b1], tev[b1]), r[(size_t)i * K_ + k]);
        mycol[i] = ((unsigned)f2bf(td * p) << 16) | f2bf(p);
      }
      float slocal = 0.f;
      for (int i = N_ - 1; i >= 0; --i) {  // backward: S, loss, tail undo
        unsigned q = mycol[i];
        slocal += bfhi(q);
        float retrace = slocal / fmaxf(bflo(q), 1e-10f);
        float qv = sv[(size_t)i * K_ + k];
        loss += sl1(qv - retrace);
        if (i >= MROWS) loss -= sl1(qv);  // role B already added this
      }
      // role A skipped alive columns entirely, so no double count.
    }
    block_reduce_store(loss, partials + bid);
  }
}

// ---------------------------------------------------------------- k4
// Single block: f64 sum of the 2568 per-block partials, write mean.
__global__ __launch_bounds__(256) void k4(const float* __restrict__ partials,
                                          float* __restrict__ out) {
  double d = 0.0;
  for (int i = threadIdx.x; i < NBTOT; i += 256) d += (double)partials[i];
  for (int off = 32; off > 0; off >>= 1) d += __shfl_down(d, off);
  __shared__ double wsum[4];
  const int lane = threadIdx.x & 63, wid = threadIdx.x >> 6;
  if (lane == 0) wsum[wid] = d;
  __syncthreads();
  if (threadIdx.x == 0) {
    double s = wsum[0] + wsum[1] + wsum[2] + wsum[3];
    out[0] = (float)(s * (1.0 / ((double)N_ * (double)K_)));
  }
}

extern "C" void kernel_launch(void* const* d_in, const int* in_sizes, int n_in,
                              void* d_out, int out_size, void* d_ws,
                              size_t ws_size, hipStream_t stream) {
  const float* sv = (const float*)d_in[0];
  const float* tsv = (const float*)d_in[1];
  const float* tev = (const float*)d_in[2];
  const float* r = (const float*)d_in[3];
  const float* ologp = (const float*)d_in[4];
  const float* tlogp = (const float*)d_in[5];

  // ws layout (~73 MB, same as R10; harness provided >= 75.5 MB R2-R10).
  // Ctrl arrays on separate pages (R9 lesson). cst/tdst ALIAS the front of
  // pkFull: they are dead before kApply role C could ever write pkFull.
  char* w = (char*)d_ws;
  unsigned long long* flag64 = (unsigned long long*)w;  // 32 u64, page 0
  float* partials = (float*)(w + 4096);                 // 2568 f32
  w += 4096 + 16384;
  unsigned* pkPre = (unsigned*)w;  // 512*2048*4 = 4 MB
  w += (size_t)MROWS * K_ * 4;
  float* P = (float*)w;  // 64*2048*4 = 512 KB each
  w += (size_t)MCH * K_ * 4;
  float* Zl = (float*)w;
  w += (size_t)MCH * K_ * 4;
  float* D0 = (float*)w;
  w += (size_t)MCH * K_ * 4;
  float* Ssuf = (float*)w;
  w += (size_t)MCH * K_ * 4;
  unsigned* pkFull = (unsigned*)w;  // 67 MB (role-C fallback only)
  float* cst = (float*)pkFull;      // 4 MB, aliases pkFull (dead by kApply)
  unsigned short* tdst = (unsigned short*)(pkFull + (size_t)MROWS * K_);

  kStage<<<PREF4 / 256, 256, 0, stream>>>(tsv, tev, r, ologp, tlogp, cst,
                                          tdst);
  kChain<<<NBPRE, 256, 0, stream>>>(cst, tdst, pkPre, P, Zl);
  kScan<<<K_ / 256, 256, 0, stream>>>(P, Zl, D0, Ssuf, flag64);
  kApply<<<NBTOT, 256, 0, stream>>>(sv, tsv, tev, r, ologp, tlogp, pkPre, D0,
                                    Ssuf, flag64, pkFull, partials);
  k4<<<1, 256, 0, stream>>>(partials, (float*)d_out);
}

// Round 12
// 31.029 us; speedup vs baseline: 1.6791x; 1.6791x over previous
//
#include <hip/hip_runtime.h>

// Retrace loss: T=8192, K=2048, gamma=0.99.
// decay = cumprod(gamma*iw); S = reverse-cumsum(td*decay);
// retrace = S / max(decay,1e-10); loss = mean(smooth_l1(q, retrace)).
//
// f32 decay underflows to EXACT 0 within ~170 rows for every column
// (E[ln c]=-0.574, sd 0.83/step; at row 512 log-decay = -294 +- 18.7 =>
// alive prob ~1e-24). Once decay==0, retrace==0 in both our and the
// reference's arithmetic (absmax 0.0, rounds 6-11).
//
// Structure lessons (hard-won):
//  R7 : latency-bound chain co-scheduled with a BW flood stretches 5x.
//  R8 : __threadfence ticket in a wide grid = L2 writeback storm (448us).
//  R9 : single-address f64 atomics serialize ~20ns each (2560 -> 50us).
//  R10: zero-atomic partials + 4 launches -> 48.2us.
//  R11: kPre split into stage+chain = +1 launch + round-trip -> 52.1us.
//       Steady state is L3-resident; time tracks LAUNCH COUNT (~9us each).
// R12: 3 launches. kScan eliminated: role A inline-scans P/Zl (R7-kF2
//      proven order); role B unconditional (role C subtracts its assumed
//      terms for alive cols); role C inline alive check. Zero atomics.

#define GAMMA 0.99f

constexpr int T_ = 8192;
constexpr int K_ = 2048;
constexpr int N_ = T_ - 1;               // 8191
constexpr int MROWS = 512;               // exact-prefix length
constexpr int L_ = 8;                    // rows per chunk
constexpr int MCH = MROWS / L_;          // 64 chunks
constexpr int NBPRE = MCH * (K_ / 256);  // 512 blocks (kPre and role A)
constexpr int NBTAIL = 2048;             // role-B blocks
constexpr int NBC = K_ / 256;            // 8 role-C blocks
constexpr int NBTOT = NBPRE + NBTAIL + NBC;  // 2568
constexpr long long TAILF4 = (long long)(N_ - MROWS) * K_ / 4;  // 3,931,648

typedef float f4 __attribute__((ext_vector_type(4)));
typedef unsigned short us4 __attribute__((ext_vector_type(4)));

__device__ __forceinline__ unsigned short f2bf(float f) {  // RTNE
  unsigned u = __float_as_uint(f);
  u += 0x7FFFu + ((u >> 16) & 1u);
  return (unsigned short)(u >> 16);
}
__device__ __forceinline__ float bf2f(unsigned short h) {
  return __uint_as_float(((unsigned)h) << 16);
}
__device__ __forceinline__ float bfhi(unsigned q) {  // y in hi16
  return __uint_as_float(q & 0xFFFF0000u);
}
__device__ __forceinline__ float bflo(unsigned q) {  // ld in lo16
  return __uint_as_float(q << 16);
}
__device__ __forceinline__ float sl1(float dd) {
  float ad = fabsf(dd);
  return (ad < 1.f) ? 0.5f * dd * dd : ad - 0.5f;
}
// Block sum -> partials[bid] (plain store, no atomics).
__device__ __forceinline__ void block_reduce_store(float l, float* slot) {
  for (int off = 32; off > 0; off >>= 1) l += __shfl_down(l, off);
  __shared__ float wsum[4];
  const int lane = threadIdx.x & 63, wid = threadIdx.x >> 6;
  if (lane == 0) wsum[wid] = l;
  __syncthreads();
  if (threadIdx.x == 0) *slot = wsum[0] + wsum[1] + wsum[2] + wsum[3];
}

// ---------------------------------------------------------------- kPre
// 8x256 tile of rows [0,512). Grid: 512 blocks (chunk = bid>>3, colblock
// = bid&7). Phase 1: waves stream rows (depth-1 pipeline, no chain near
// loads); phase 2: per-column f32 chain, packed bf16 (y|ld) store +
// chunk summaries P, Zl. Numerics proven (absmax 0.0, R8-R11).
__global__ __launch_bounds__(256) void kPre(
    const float* __restrict__ tsv, const float* __restrict__ tev,
    const float* __restrict__ r, const float* __restrict__ ologp,
    const float* __restrict__ tlogp, unsigned* __restrict__ pkPre,
    float* __restrict__ P, float* __restrict__ Zl) {
  __shared__ float csh[L_][256];            // f32 c (exact chain)
  __shared__ unsigned short tdsh[L_][256];  // bf16 td
  const int tid = threadIdx.x;
  const int lane = tid & 63;
  const int wid = tid >> 6;
  const int c0 = (blockIdx.x & 7) * 256;
  const int chunk = blockIdx.x >> 3;
  const int i0 = chunk * L_;
  const int col = c0 + lane * 4;

  f4 lwA, aA, vA, rrA;
  float oA;
  auto issue = [&](int s, f4& lw, f4& a, f4& v, f4& rr, float& o) {
    const int i = i0 + s;
    const size_t b1 = (size_t)(i + 1) * K_ + col;
    const size_t b0 = (size_t)i * K_ + col;
    lw = *(const f4*)(tlogp + b1);
    a = *(const f4*)(tsv + b1);
    v = *(const f4*)(tev + b1);
    rr = *(const f4*)(r + b0);
    o = ologp[i + 1];
  };
  issue(wid, lwA, aA, vA, rrA, oA);
#pragma unroll
  for (int s0 = 0; s0 < L_; s0 += 4) {
    const int s = s0 + wid;
    f4 lwB, aB, vB, rrB;
    float oB;
    if (s0 + 4 < L_) issue(s + 4, lwB, aB, vB, rrB, oB);
    __builtin_amdgcn_sched_barrier(0);
    f4 iw, c, td;
#pragma unroll
    for (int x = 0; x < 4; ++x) iw[x] = __expf(fminf(lwA[x] - oA, 0.f));
#pragma unroll
    for (int x = 0; x < 4; ++x) c[x] = GAMMA * iw[x];
#pragma unroll
    for (int x = 0; x < 4; ++x)
      td[x] = fmaf(GAMMA, fmaf(-iw[x], aA[x], vA[x]), rrA[x]);
    *(f4*)&csh[s][lane * 4] = c;
    us4 t4;
#pragma unroll
    for (int x = 0; x < 4; ++x) t4[x] = f2bf(td[x]);
    *(us4*)&tdsh[s][lane * 4] = t4;
    if (s0 + 4 < L_) {
      lwA = lwB;
      aA = aB;
      vA = vB;
      rrA = rrB;
      oA = oB;
    }
  }
  __syncthreads();

  const int kcol = c0 + tid;
  float p = 1.f, zl = 0.f;
#pragma unroll
  for (int s = 0; s < L_; ++s) {
    p *= csh[s][tid];
    float y = bf2f(tdsh[s][tid]) * p;
    zl += y;
    pkPre[(size_t)(i0 + s) * K_ + kcol] = ((unsigned)f2bf(y) << 16) | f2bf(p);
  }
  P[(size_t)chunk * K_ + kcol] = p;
  Zl[(size_t)chunk * K_ + kcol] = zl;
}

// ---------------------------------------------------------------- kApply
// Role A: prefix apply with INLINE chunk scan over P/Zl (L2-hot, 512 KB;
//   forward-order ssuf accumulation proven in R7-kF2, absmax 0.0).
// Role B: tail sl1(sv), UNCONDITIONAL (all columns).
// Role C: inline alive check; exact serial fallback per alive column,
//   subtracting role B's assumed terms (never taken for this data).
// Every block writes its own partials slot. NO atomics, NO fences.
__global__ __launch_bounds__(256) void kApply(
    const float* __restrict__ sv, const float* __restrict__ tsv,
    const float* __restrict__ tev, const float* __restrict__ r,
    const float* __restrict__ ologp, const float* __restrict__ tlogp,
    const unsigned* __restrict__ pkPre, const float* __restrict__ P,
    const float* __restrict__ Zl, unsigned* __restrict__ pkFull,
    float* __restrict__ partials) {
  const int bid = blockIdx.x;
  const int tid = threadIdx.x;

  if (bid < NBPRE) {  // ---- role A: prefix rows [0,512)
    const int myc = bid >> 3;
    const int k = (bid & 7) * 256 + tid;
    // inline scan: d0 = prod_{c<myc} P_c ; dj = full product (alive test)
    float d0 = 1.f, dj = 1.f;
#pragma unroll 16
    for (int c = 0; c < MCH; ++c) {
      if (c == myc) d0 = dj;
      dj *= P[(size_t)c * K_ + k];
    }
    float loss = 0.f;
    if (dj == 0.f) {  // dead column (typical): chunked result is exact
      float ssuf = 0.f;
      float dp = d0 * P[(size_t)myc * K_ + k];
      for (int c = myc + 1; c < MCH; ++c) {
        ssuf = fmaf(dp, Zl[(size_t)c * K_ + k], ssuf);
        dp *= P[(size_t)c * K_ + k];
      }
      const int i0 = myc * L_;
      float slocal = 0.f;
#pragma unroll
      for (int s = L_ - 1; s >= 0; --s) {
        const size_t b0 = (size_t)(i0 + s) * K_ + k;
        unsigned q = pkPre[b0];
        slocal += bfhi(q);
        float S = fmaf(d0, slocal, ssuf);
        float retrace = S / fmaxf(d0 * bflo(q), 1e-10f);
        loss += sl1(sv[b0] - retrace);
      }
    }
    block_reduce_store(loss, partials + bid);
  } else if (bid < NBPRE + NBTAIL) {  // ---- role B: tail, unconditional
    const long long base = (long long)MROWS * K_ / 4;  // f4 offset
    float loss = 0.f;
    for (long long v = (long long)(bid - NBPRE) * 256 + tid; v < TAILF4;
         v += (long long)NBTAIL * 256) {
      f4 q = ((const f4*)sv)[base + v];
#pragma unroll
      for (int x = 0; x < 4; ++x) loss += sl1(q[x]);
    }
    block_reduce_store(loss, partials + bid);
  } else {  // ---- role C: thread per column; inline alive check
    const int k = (bid - NBPRE - NBTAIL) * 256 + tid;
    float loss = 0.f;
    float dj = 1.f;
#pragma unroll 16
    for (int c = 0; c < MCH; ++c) dj *= P[(size_t)c * K_ + k];
    if (dj != 0.f) {  // alive (never for this data): exact recompute
      unsigned* mycol = pkFull + (size_t)k * 8192;
      float p = 1.f;
      for (int i = 0; i < N_; ++i) {  // forward: exact sequential decay
        const size_t b1 = (size_t)(i + 1) * K_ + k;
        float iw = __expf(fminf(tlogp[b1] - ologp[i + 1], 0.f));
        p *= GAMMA * iw;
        float td =
            fmaf(GAMMA, fmaf(-iw, tsv[b1], tev[b1]), r[(size_t)i * K_ + k]);
        mycol[i] = ((unsigned)f2bf(td * p) << 16) | f2bf(p);
      }
      float slocal = 0.f;
      for (int i = N_ - 1; i >= 0; --i) {  // backward: S, loss, tail undo
        unsigned q = mycol[i];
        slocal += bfhi(q);
        float retrace = slocal / fmaxf(bflo(q), 1e-10f);
        float qv = sv[(size_t)i * K_ + k];
        loss += sl1(qv - retrace);
        if (i >= MROWS) loss -= sl1(qv);  // role B added this for ALL cols
      }
      // role A contributed 0 for alive columns (dj != 0 skip) -> no dup.
    }
    block_reduce_store(loss, partials + bid);
  }
}

// ---------------------------------------------------------------- k4
// Single block: f64 sum of the 2568 per-block partials, write mean.
__global__ __launch_bounds__(256) void k4(const float* __restrict__ partials,
                                          float* __restrict__ out) {
  double d = 0.0;
  for (int i = threadIdx.x; i < NBTOT; i += 256) d += (double)partials[i];
  for (int off = 32; off > 0; off >>= 1) d += __shfl_down(d, off);
  __shared__ double wsum[4];
  const int lane = threadIdx.x & 63, wid = threadIdx.x >> 6;
  if (lane == 0) wsum[wid] = d;
  __syncthreads();
  if (threadIdx.x == 0) {
    double s = wsum[0] + wsum[1] + wsum[2] + wsum[3];
    out[0] = (float)(s * (1.0 / ((double)N_ * (double)K_)));
  }
}

extern "C" void kernel_launch(void* const* d_in, const int* in_sizes, int n_in,
                              void* d_out, int out_size, void* d_ws,
                              size_t ws_size, hipStream_t stream) {
  const float* sv = (const float*)d_in[0];
  const float* tsv = (const float*)d_in[1];
  const float* tev = (const float*)d_in[2];
  const float* r = (const float*)d_in[3];
  const float* ologp = (const float*)d_in[4];
  const float* tlogp = (const float*)d_in[5];

  // ws layout (~72 MB; harness provided >= 75.5 MB rounds 2-11).
  // partials on its own page (R9 lesson: no ctrl-line sharing).
  char* w = (char*)d_ws;
  float* partials = (float*)w;  // 2568 f32, page 0
  w += 16384;
  unsigned* pkPre = (unsigned*)w;  // 512*2048*4 = 4 MB
  w += (size_t)MROWS * K_ * 4;
  float* P = (float*)w;  // 64*2048*4 = 512 KB each
  w += (size_t)MCH * K_ * 4;
  float* Zl = (float*)w;
  w += (size_t)MCH * K_ * 4;
  unsigned* pkFull = (unsigned*)w;  // 67 MB (role-C fallback only)

  kPre<<<NBPRE, 256, 0, stream>>>(tsv, tev, r, ologp, tlogp, pkPre, P, Zl);
  kApply<<<NBTOT, 256, 0, stream>>>(sv, tsv, tev, r, ologp, tlogp, pkPre, P,
                                    Zl, pkFull, partials);
  k4<<<1, 256, 0, stream>>>(partials, (float*)d_out);
}

// Round 13
// 27.867 us; speedup vs baseline: 1.8696x; 1.1135x over previous
//
#include <hip/hip_runtime.h>

// Retrace loss: T=8192, K=2048, gamma=0.99.
// decay = cumprod(gamma*iw); S = reverse-cumsum(td*decay);
// retrace = S / max(decay,1e-10); loss = mean(smooth_l1(q, retrace)).
//
// f32 decay underflows to EXACT 0 fast (E[ln c]=-0.574, sd 0.83/step; at
// row 384 log-decay = -220 +- 16.3 vs f32 denorm floor -103 => alive needs
// +7.2 sigma, P ~ 6e-10 across all 2048 columns). Once decay==0,
// retrace==0 in both our and the reference's arithmetic (absmax 0.0,
// rounds 6-12). Role C is the exact fallback if a column ever survives.
//
// Structure lessons (hard-won):
//  R7 : latency chain co-scheduled with a BW flood stretches 5x.
//  R8 : __threadfence ticket in a wide grid = L2 writeback storm (448us).
//  R9 : single-address f64 atomics + shared ctrl cacheline = 50us.
//  R10: zero-atomic partials, 4 launches -> 48.2us.
//  R11: +1 launch (stage/chain split) -> 52.1us. Time tracks LAUNCH COUNT.
//  R12: 3 launches, kScan inlined into role A -> 31.0us.
//  R13: kPre register-only (no LDS/barrier; 32 independent coalesced
//       loads/thread then register chain) + MROWS 512->384.

#define GAMMA 0.99f

constexpr int T_ = 8192;
constexpr int K_ = 2048;
constexpr int N_ = T_ - 1;               // 8191
constexpr int MROWS = 384;               // exact-prefix length
constexpr int L_ = 8;                    // rows per chunk
constexpr int MCH = MROWS / L_;          // 48 chunks
constexpr int NBPRE = MCH * (K_ / 256);  // 384 blocks (kPre and role A)
constexpr int NBTAIL = 2048;             // role-B blocks
constexpr int NBC = K_ / 256;            // 8 role-C blocks
constexpr int NBTOT = NBPRE + NBTAIL + NBC;  // 2440
constexpr long long TAILF4 = (long long)(N_ - MROWS) * K_ / 4;  // 3,997,184

typedef float f4 __attribute__((ext_vector_type(4)));

__device__ __forceinline__ unsigned short f2bf(float f) {  // RTNE
  unsigned u = __float_as_uint(f);
  u += 0x7FFFu + ((u >> 16) & 1u);
  return (unsigned short)(u >> 16);
}
__device__ __forceinline__ float bf2f(unsigned short h) {
  return __uint_as_float(((unsigned)h) << 16);
}
__device__ __forceinline__ float bfhi(unsigned q) {  // y in hi16
  return __uint_as_float(q & 0xFFFF0000u);
}
__device__ __forceinline__ float bflo(unsigned q) {  // ld in lo16
  return __uint_as_float(q << 16);
}
__device__ __forceinline__ float sl1(float dd) {
  float ad = fabsf(dd);
  return (ad < 1.f) ? 0.5f * dd * dd : ad - 0.5f;
}
// Block sum -> partials[bid] (plain store, no atomics).
__device__ __forceinline__ void block_reduce_store(float l, float* slot) {
  for (int off = 32; off > 0; off >>= 1) l += __shfl_down(l, off);
  __shared__ float wsum[4];
  const int lane = threadIdx.x & 63, wid = threadIdx.x >> 6;
  if (lane == 0) wsum[wid] = l;
  __syncthreads();
  if (threadIdx.x == 0) *slot = wsum[0] + wsum[1] + wsum[2] + wsum[3];
}

// ---------------------------------------------------------------- kPre
// Register-only: thread = (chunk, col). 32 independent coalesced 4B loads
// (8 rows x {tlogp,tsv,tev,r}) issued up front (8KB/wave in flight), then
// the f32 chain in registers. Op order identical to the proven LDS path
// (c stays f32; td through bf16 round-trip). No LDS, no barrier.
__global__ __launch_bounds__(256) void kPre(
    const float* __restrict__ tsv, const float* __restrict__ tev,
    const float* __restrict__ r, const float* __restrict__ ologp,
    const float* __restrict__ tlogp, unsigned* __restrict__ pkPre,
    float* __restrict__ P, float* __restrict__ Zl) {
  const int chunk = blockIdx.x >> 3;  // 0..MCH-1
  const int k = (blockIdx.x & 7) * 256 + threadIdx.x;
  const int i0 = chunk * L_;

  float lw[L_], a[L_], v[L_], rr[L_], o[L_];
#pragma unroll
  for (int s = 0; s < L_; ++s) {  // all loads independent -> MLP
    const int i = i0 + s;
    const size_t b1 = (size_t)(i + 1) * K_ + k;
    lw[s] = tlogp[b1];
    a[s] = tsv[b1];
    v[s] = tev[b1];
    rr[s] = r[(size_t)i * K_ + k];
    o[s] = ologp[i + 1];  // block-uniform -> scalar load
  }
  float p = 1.f, zl = 0.f;
#pragma unroll
  for (int s = 0; s < L_; ++s) {
    float iw = __expf(fminf(lw[s] - o[s], 0.f));
    float c = GAMMA * iw;  // f32, same as LDS-path csh
    p *= c;
    float td = fmaf(GAMMA, fmaf(-iw, a[s], v[s]), rr[s]);
    float tdb = bf2f(f2bf(td));  // bf16 round-trip, same as tdsh path
    float y = tdb * p;
    zl += y;
    pkPre[(size_t)(i0 + s) * K_ + k] = ((unsigned)f2bf(y) << 16) | f2bf(p);
  }
  P[(size_t)chunk * K_ + k] = p;
  Zl[(size_t)chunk * K_ + k] = zl;
}

// ---------------------------------------------------------------- kApply
// Role A: prefix apply with INLINE chunk scan over P/Zl (L2-hot;
//   forward-order ssuf accumulation proven R7/R12, absmax 0.0).
// Role B: tail sl1(sv), UNCONDITIONAL (all columns).
// Role C: inline alive check; exact serial fallback per alive column,
//   subtracting role B's assumed terms (never taken for this data).
// Every block writes its own partials slot. NO atomics, NO fences.
__global__ __launch_bounds__(256) void kApply(
    const float* __restrict__ sv, const float* __restrict__ tsv,
    const float* __restrict__ tev, const float* __restrict__ r,
    const float* __restrict__ ologp, const float* __restrict__ tlogp,
    const unsigned* __restrict__ pkPre, const float* __restrict__ P,
    const float* __restrict__ Zl, unsigned* __restrict__ pkFull,
    float* __restrict__ partials) {
  const int bid = blockIdx.x;
  const int tid = threadIdx.x;

  if (bid < NBPRE) {  // ---- role A: prefix rows [0,MROWS)
    const int myc = bid >> 3;
    const int k = (bid & 7) * 256 + tid;
    // inline scan: d0 = prod_{c<myc} P_c ; dj = full product (alive test)
    float d0 = 1.f, dj = 1.f;
#pragma unroll 16
    for (int c = 0; c < MCH; ++c) {
      if (c == myc) d0 = dj;
      dj *= P[(size_t)c * K_ + k];
    }
    float loss = 0.f;
    if (dj == 0.f) {  // dead column (typical): chunked result is exact
      float ssuf = 0.f;
      float dp = d0 * P[(size_t)myc * K_ + k];
      for (int c = myc + 1; c < MCH; ++c) {
        ssuf = fmaf(dp, Zl[(size_t)c * K_ + k], ssuf);
        dp *= P[(size_t)c * K_ + k];
      }
      const int i0 = myc * L_;
      float slocal = 0.f;
#pragma unroll
      for (int s = L_ - 1; s >= 0; --s) {
        const size_t b0 = (size_t)(i0 + s) * K_ + k;
        unsigned q = pkPre[b0];
        slocal += bfhi(q);
        float S = fmaf(d0, slocal, ssuf);
        float retrace = S / fmaxf(d0 * bflo(q), 1e-10f);
        loss += sl1(sv[b0] - retrace);
      }
    }
    block_reduce_store(loss, partials + bid);
  } else if (bid < NBPRE + NBTAIL) {  // ---- role B: tail, unconditional
    const long long base = (long long)MROWS * K_ / 4;  // f4 offset
    float loss = 0.f;
    for (long long v = (long long)(bid - NBPRE) * 256 + tid; v < TAILF4;
         v += (long long)NBTAIL * 256) {
      f4 q = ((const f4*)sv)[base + v];
#pragma unroll
      for (int x = 0; x < 4; ++x) loss += sl1(q[x]);
    }
    block_reduce_store(loss, partials + bid);
  } else {  // ---- role C: thread per column; inline alive check
    const int k = (bid - NBPRE - NBTAIL) * 256 + tid;
    float loss = 0.f;
    float dj = 1.f;
#pragma unroll 16
    for (int c = 0; c < MCH; ++c) dj *= P[(size_t)c * K_ + k];
    if (dj != 0.f) {  // alive (never for this data): exact recompute
      unsigned* mycol = pkFull + (size_t)k * 8192;
      float p = 1.f;
      for (int i = 0; i < N_; ++i) {  // forward: exact sequential decay
        const size_t b1 = (size_t)(i + 1) * K_ + k;
        float iw = __expf(fminf(tlogp[b1] - ologp[i + 1], 0.f));
        p *= GAMMA * iw;
        float td =
            fmaf(GAMMA, fmaf(-iw, tsv[b1], tev[b1]), r[(size_t)i * K_ + k]);
        mycol[i] = ((unsigned)f2bf(td * p) << 16) | f2bf(p);
      }
      float slocal = 0.f;
      for (int i = N_ - 1; i >= 0; --i) {  // backward: S, loss, tail undo
        unsigned q = mycol[i];
        slocal += bfhi(q);
        float retrace = slocal / fmaxf(bflo(q), 1e-10f);
        float qv = sv[(size_t)i * K_ + k];
        loss += sl1(qv - retrace);
        if (i >= MROWS) loss -= sl1(qv);  // role B added this for ALL cols
      }
      // role A contributed 0 for alive columns (dj != 0 skip) -> no dup.
    }
    block_reduce_store(loss, partials + bid);
  }
}

// ---------------------------------------------------------------- k4
// Single block: f64 sum of the 2440 per-block partials, write mean.
__global__ __launch_bounds__(256) void k4(const float* __restrict__ partials,
                                          float* __restrict__ out) {
  double d = 0.0;
  for (int i = threadIdx.x; i < NBTOT; i += 256) d += (double)partials[i];
  for (int off = 32; off > 0; off >>= 1) d += __shfl_down(d, off);
  __shared__ double wsum[4];
  const int lane = threadIdx.x & 63, wid = threadIdx.x >> 6;
  if (lane == 0) wsum[wid] = d;
  __syncthreads();
  if (threadIdx.x == 0) {
    double s = wsum[0] + wsum[1] + wsum[2] + wsum[3];
    out[0] = (float)(s * (1.0 / ((double)N_ * (double)K_)));
  }
}

extern "C" void kernel_launch(void* const* d_in, const int* in_sizes, int n_in,
                              void* d_out, int out_size, void* d_ws,
                              size_t ws_size, hipStream_t stream) {
  const float* sv = (const float*)d_in[0];
  const float* tsv = (const float*)d_in[1];
  const float* tev = (const float*)d_in[2];
  const float* r = (const float*)d_in[3];
  const float* ologp = (const float*)d_in[4];
  const float* tlogp = (const float*)d_in[5];

  // ws layout (~71 MB; harness provided >= 75.5 MB rounds 2-12).
  // partials on its own page (R9 lesson: no ctrl-line sharing).
  char* w = (char*)d_ws;
  float* partials = (float*)w;  // 2440 f32, page 0
  w += 16384;
  unsigned* pkPre = (unsigned*)w;  // 384*2048*4 = 3 MB
  w += (size_t)MROWS * K_ * 4;
  float* P = (float*)w;  // 48*2048*4 = 384 KB each
  w += (size_t)MCH * K_ * 4;
  float* Zl = (float*)w;
  w += (size_t)MCH * K_ * 4;
  unsigned* pkFull = (unsigned*)w;  // 67 MB (role-C fallback only)

  kPre<<<NBPRE, 256, 0, stream>>>(tsv, tev, r, ologp, tlogp, pkPre, P, Zl);
  kApply<<<NBTOT, 256, 0, stream>>>(sv, tsv, tev, r, ologp, tlogp, pkPre, P,
                                    Zl, pkFull, partials);
  k4<<<1, 256, 0, stream>>>(partials, (float*)d_out);
}